// Round 5
// baseline (80.439 us; speedup 1.0000x reference)
//
#include <hip/hip_runtime.h>
#include <hip/hip_bf16.h>

// FConv2d exact reduced form:
// out[b, d*16+n, r, s] =
//   0.5 * sum_{c2<32,u,v<3} W[n,c2,2-u,2-v] * (xa + xb)[r+u, s+v]
// xa = x[b,(8d-c2)%128], xb = x[b,(-8d-c2)%128], zero outside 32x32.
// (FFT pipeline == symmetrized inverse channel-DFT + 3x3 correlation;
//  verified: round 3 fp32 absmax 7.8e-3, round 4 bf16-MFMA absmax 1.6e-2.)
//
// NEW (round 5): cos(2*pi*8d*c/128) is even in d (mod 16)  =>
// xcomb[16-d] == xcomb[d]  =>  out channels (16-d)*16+n duplicate d*16+n.
// Compute d=0..8 only, mirror-write d=9..15.  44% less work.
// LDS row stride 35 units (16B each): staging-write bank groups
// (3r+4sq+c) mod 8 and MFMA-read groups (6q+3r+c) mod 8 are uniform ->
// conflict-free (was 4-way on writes at stride 34).

typedef __attribute__((ext_vector_type(8))) short short8;
typedef __attribute__((ext_vector_type(4))) short short4v;
typedef __attribute__((ext_vector_type(4))) float floatx4;

#define NT 512

static __device__ __forceinline__ short bf16bits(float f) {
    __hip_bfloat16 h = __float2bfloat16(f);
    return __builtin_bit_cast(short, h);
}

__global__ __launch_bounds__(NT, 4)
void fconv_mfma(const float* __restrict__ x,
                const float* __restrict__ wgt,
                float* __restrict__ out) {
    // xs[oct][r][s][j]: oct = c2 octet (4), r = 0..17, s = 0..34 (stride 35), j = c2 in octet
    __shared__ short xs[4 * 18 * 35 * 8];   // 40320 B

    const int half = blockIdx.x;    // 0..1 : 16-row half band
    const int d    = blockIdx.y;    // 0..8
    const int b    = blockIdx.z;    // 0..15
    const int r0   = half * 16;
    const int tid  = threadIdx.x;

    // ---- stage xcomb = 0.5*(xa+xb) as bf16, layout [oct][r][s][8] ----
    // task = (c2 quad, input row, s quad): 8 * 18 * 8 = 1152 tasks
#pragma unroll
    for (int it = 0; it < 3; ++it) {
        const int task = tid + it * NT;
        if (task < 1152) {
            const int c2q = task / 144;           // 0..7 (4 c2 each)
            const int rem = task - c2q * 144;
            const int r   = rem >> 3;             // 0..17
            const int sq  = rem & 7;              // 0..7 (4 s each)
            const int gr  = r0 + r;
            short vals[4][4];                     // [cc][ss]
            if (gr < 32) {
#pragma unroll
                for (int cc = 0; cc < 4; ++cc) {
                    const int c2  = c2q * 4 + cc;
                    const int c1a = (8 * d - c2) & 127;
                    const int c1b = (-8 * d - c2) & 127;
                    const float4 A = *(const float4*)(x + (size_t)((b * 128 + c1a) * 1024 + gr * 32 + sq * 4));
                    const float4 B = *(const float4*)(x + (size_t)((b * 128 + c1b) * 1024 + gr * 32 + sq * 4));
                    vals[cc][0] = bf16bits(0.5f * (A.x + B.x));
                    vals[cc][1] = bf16bits(0.5f * (A.y + B.y));
                    vals[cc][2] = bf16bits(0.5f * (A.z + B.z));
                    vals[cc][3] = bf16bits(0.5f * (A.w + B.w));
                }
            } else {
#pragma unroll
                for (int cc = 0; cc < 4; ++cc)
#pragma unroll
                    for (int ss = 0; ss < 4; ++ss) vals[cc][ss] = 0;
            }
            const int octet = c2q >> 1;
            const int hb    = (c2q & 1) * 4;
#pragma unroll
            for (int ss = 0; ss < 4; ++ss) {
                const int s = sq * 4 + ss;
                short4v p;
                p.x = vals[0][ss]; p.y = vals[1][ss];
                p.z = vals[2][ss]; p.w = vals[3][ss];
                *(short4v*)&xs[(((octet * 18 + r) * 35 + s) << 3) + hb] = p;
            }
        }
    }
    // s-apron (s = 32,33) zeros
    if (tid < 144) {
        const int r  = tid >> 3;
        const int k  = tid & 7;
        const int s  = 32 + (k >> 2);
        const int oc = k & 3;
        short8 z = {0, 0, 0, 0, 0, 0, 0, 0};
        *(short8*)&xs[((oc * 18 + r) * 35 + s) << 3] = z;
    }

    // ---- A fragments (flipped weights) in registers ----
    const int lane = tid & 63;
    const int c    = lane & 15;     // A: m=n index; B: col; D: col
    const int q    = lane >> 4;     // k-octet select; D: row group
    short8 af[9];
#pragma unroll
    for (int u = 0; u < 3; ++u)
#pragma unroll
        for (int v = 0; v < 3; ++v) {
            short8 f;
#pragma unroll
            for (int j = 0; j < 8; ++j) {
                const int c2 = q * 8 + j;
                f[j] = bf16bits(wgt[((c * 32 + c2) * 3 + (2 - u)) * 3 + (2 - v)]);
            }
            af[u * 3 + v] = f;
        }

    __syncthreads();

    // ---- compute: wave w does 4 tiles (2 rows x 2 col-halves) ----
    const int w = tid >> 6;
#pragma unroll
    for (int i = 0; i < 4; ++i) {
        const int lr = 2 * w + (i >> 1);      // local output row 0..15
        const int s0 = (i & 1) << 4;          // 0 or 16
        floatx4 acc = {0.f, 0.f, 0.f, 0.f};
        const short* basep = &xs[(q * 630 + lr * 35 + s0 + c) << 3];
#pragma unroll
        for (int u = 0; u < 3; ++u)
#pragma unroll
            for (int v = 0; v < 3; ++v) {
                const short8 bf = *(const short8*)(basep + ((u * 35 + v) << 3));
                acc = __builtin_amdgcn_mfma_f32_16x16x32_bf16(af[u * 3 + v], bf, acc, 0, 0, 0);
            }
        // D: col = c (s = s0+c), row = q*4+reg (n)
        float* op = out + (size_t)(((b * 256 + d * 16 + q * 4) * 32 + (r0 + lr)) * 32 + s0 + c);
        op[0]    = acc.x;
        op[1024] = acc.y;
        op[2048] = acc.z;
        op[3072] = acc.w;
        if (d >= 1 && d <= 7) {   // mirror channel group (16-d)
            float* op2 = out + (size_t)(((b * 256 + (16 - d) * 16 + q * 4) * 32 + (r0 + lr)) * 32 + s0 + c);
            op2[0]    = acc.x;
            op2[1024] = acc.y;
            op2[2048] = acc.z;
            op2[3072] = acc.w;
        }
    }
}

extern "C" void kernel_launch(void* const* d_in, const int* in_sizes, int n_in,
                              void* d_out, int out_size, void* d_ws, size_t ws_size,
                              hipStream_t stream) {
    const float* x   = (const float*)d_in[0];   // (16,128,32,32) fp32
    const float* wgt = (const float*)d_in[1];   // (16,32,3,3)   fp32
    float* out = (float*)d_out;                 // (16,256,32,32) fp32
    (void)in_sizes; (void)n_in; (void)out_size; (void)d_ws; (void)ws_size;

    dim3 grid(2, 9, 16);    // (half-band, d=0..8, b)
    dim3 block(NT);
    fconv_mfma<<<grid, block, 0, stream>>>(x, wgt, out);
}

// Round 6
// 79.433 us; speedup vs baseline: 1.0127x; 1.0127x over previous
//
#include <hip/hip_runtime.h>
#include <hip/hip_bf16.h>

// FConv2d exact reduced form:
// out[b, d*16+n, r, s] =
//   0.5 * sum_{c2<32,u,v<3} W[n,c2,2-u,2-v] * (xa + xb)[r+u, s+v]
// xa = x[b,(8d-c2)%128], xb = x[b,(-8d-c2)%128], zero outside 32x32;
// xcomb[16-d] == xcomb[d]  =>  compute d=0..8, mirror-write 9..15.
// (Verified: r3 fp32 7.8e-3, r4/r5 bf16-MFMA 1.56e-2 vs np ref.)
//
// Round 6: (a) weights staged cooperatively in LDS (rounds 4/5 did 72
// per-lane global gathers per thread -> ~30us/CU at the L1 port — the
// hidden dominator); (b) 576 x 256-thread blocks for smooth makespan;
// (c) staging writes are one ds_write_b128 per lane-owned granule
// (conflict-free), x loads coalesced with wave-uniform channel bases.

typedef __attribute__((ext_vector_type(8))) short short8;
typedef __attribute__((ext_vector_type(4))) float floatx4;

#define NT 256
#define SROW 34              // xs row stride in 16-B granules
#define SOCT (10 * SROW)     // 340 granules per c2-octet

static __device__ __forceinline__ short bf16bits(float f) {
    __hip_bfloat16 h = __float2bfloat16(f);
    return __builtin_bit_cast(short, h);
}

__global__ __launch_bounds__(NT, 4)
void fconv_mfma(const float* __restrict__ x,
                const float* __restrict__ wgt,
                float* __restrict__ out) {
    // xs granule (oct, r, s): 8 bf16 = c2 octet values at input (r, s)
    __shared__ __align__(16) short xs[4 * 10 * SROW * 8];   // 21760 B
    __shared__ __align__(16) short wf[9 * 16 * 32];         //  9216 B

    const int quarter = blockIdx.x;   // 0..3 : 8-row band
    const int d       = blockIdx.y;   // 0..8
    const int b       = blockIdx.z;   // 0..15
    const int r0      = quarter * 8;
    const int tid     = threadIdx.x;
    const int dup     = ((d & 7) == 0);   // d==0 or d==8: xa == xb

    const float* xb_base = x + ((size_t)b << 17);   // b*128*1024

    // ---- weights -> LDS: wf[t][n][c2] = W[n][c2][flip(t)], t=8-k ----
#pragma unroll
    for (int pp = 0; pp < 2; ++pp) {
        const int p  = tid + pp * NT;      // 0..511
        const int n  = p >> 5;
        const int c2 = p & 31;
        const float* wb = wgt + (size_t)(n * 32 + c2) * 9;
#pragma unroll
        for (int k = 0; k < 9; ++k)
            wf[(8 - k) * 512 + n * 32 + c2] = bf16bits(wb[k]);
    }

    // ---- stage xcomb granules: 1280 tasks (oct, r, s) ----
#pragma unroll
    for (int it = 0; it < 5; ++it) {
        const int task = tid + it * NT;       // 0..1279
        const int oct  = task / 320;          // wave-uniform (320 % 64 == 0)
        const int rem  = task - oct * 320;
        const int r    = rem >> 5;            // 0..9
        const int s    = rem & 31;
        const int gr   = r0 + r;
        short8 g;
        if (gr < 32) {
            const int off = (gr << 5) + s;
#pragma unroll
            for (int j = 0; j < 8; ++j) {
                const int c2  = oct * 8 + j;
                const int c1a = (8 * d - c2) & 127;
                const float va = xb_base[(c1a << 10) + off];
                float v;
                if (dup) {
                    v = va;
                } else {
                    const int c1b = (-8 * d - c2) & 127;
                    const float vb = xb_base[(c1b << 10) + off];
                    v = 0.5f * (va + vb);
                }
                g[j] = bf16bits(v);
            }
        } else {
#pragma unroll
            for (int j = 0; j < 8; ++j) g[j] = 0;
        }
        *(short8*)&xs[(oct * SOCT + r * SROW + s) << 3] = g;
    }
    // s-apron (s = 32, 33) zeros: 4 oct * 10 r * 2 s = 80 granules
    if (tid < 80) {
        const int oct = tid / 20;
        const int rem = tid - oct * 20;
        const int r   = rem >> 1;
        const int s   = 32 + (rem & 1);
        short8 z = {0, 0, 0, 0, 0, 0, 0, 0};
        *(short8*)&xs[(oct * SOCT + r * SROW + s) << 3] = z;
    }

    __syncthreads();

    // ---- A fragments from LDS: 9 conflict-free ds_read_b128 ----
    const int lane = tid & 63;
    const int c    = lane & 15;     // A: n index; B/D: col (s offset)
    const int q    = lane >> 4;     // k-octet; D: row group (n = q*4+reg)
    short8 af[9];
#pragma unroll
    for (int t = 0; t < 9; ++t)
        af[t] = *(const short8*)&wf[t * 512 + c * 32 + q * 8];

    // ---- compute: wave w does 4 tiles (2 rows x 2 col-halves) ----
    const int w = tid >> 6;
#pragma unroll
    for (int i = 0; i < 4; ++i) {
        const int lr = 2 * w + (i >> 1);      // local output row 0..7
        const int s0 = (i & 1) << 4;          // 0 or 16
        floatx4 acc = {0.f, 0.f, 0.f, 0.f};
        const short* basep = &xs[(q * SOCT + lr * SROW + s0 + c) << 3];
#pragma unroll
        for (int u = 0; u < 3; ++u)
#pragma unroll
            for (int v = 0; v < 3; ++v) {
                const short8 bf = *(const short8*)(basep + ((u * SROW + v) << 3));
                acc = __builtin_amdgcn_mfma_f32_16x16x32_bf16(af[u * 3 + v], bf, acc, 0, 0, 0);
            }
        // D: col = c (s = s0+c), row = q*4+reg (n)
        float* op = out + (size_t)(((b * 256 + d * 16 + q * 4) * 32 + (r0 + lr)) * 32 + s0 + c);
        op[0]    = acc.x;
        op[1024] = acc.y;
        op[2048] = acc.z;
        op[3072] = acc.w;
        if (d >= 1 && d <= 7) {   // mirror channel group (16-d)
            float* op2 = out + (size_t)(((b * 256 + (16 - d) * 16 + q * 4) * 32 + (r0 + lr)) * 32 + s0 + c);
            op2[0]    = acc.x;
            op2[1024] = acc.y;
            op2[2048] = acc.z;
            op2[3072] = acc.w;
        }
    }
}

extern "C" void kernel_launch(void* const* d_in, const int* in_sizes, int n_in,
                              void* d_out, int out_size, void* d_ws, size_t ws_size,
                              hipStream_t stream) {
    const float* x   = (const float*)d_in[0];   // (16,128,32,32) fp32
    const float* wgt = (const float*)d_in[1];   // (16,32,3,3)   fp32
    float* out = (float*)d_out;                 // (16,256,32,32) fp32
    (void)in_sizes; (void)n_in; (void)out_size; (void)d_ws; (void)ws_size;

    dim3 grid(4, 9, 16);    // (quarter-band, d=0..8, b)
    dim3 block(NT);
    fconv_mfma<<<grid, block, 0, stream>>>(x, wgt, out);
}